// Round 4
// baseline (464.565 us; speedup 1.0000x reference)
//
#include <hip/hip_runtime.h>

// out[t,b,n] = 1 iff any spike in window [t-duration+1, t].
// R4: two-phase through a 1-bit intermediate to DECOUPLE the big read
// stream from the big write stream (R1-R3 all pinned at ~3 TB/s with
// interleaved R/W; fill-only hits 6.5 TB/s).
//   K1: fp32 spikes -> bitmask bm[tw][col] (8.4 MB, lives in d_ws).
//       Pure 268 MB read stream + tiny write.
//   K2: windowed OR of <=5 bitmask words (L2-resident) -> fp32 out.
//       Pure 268 MB write stream + tiny read.

#define T_TOTAL 2048
#define M_COLS  (16 * 2048)        // 32768 columns, contiguous fastest axis
#define M4      (M_COLS / 4)       // 8192 float4/uint4 groups per row
#define TW      (T_TOTAL / 32)     // 64 bit-words along t per column

// ---- K1: pack spikes to bits ----
// grid (32 colblks, 64 twblks), block 256. Thread owns 4 adjacent cols,
// loops 32 t-steps; block reads 4 KB contiguous per t (strided 128 KB
// between t). 32 independent float4 loads per thread = deep MLP, no
// stores in the loop.
__global__ __launch_bounds__(256) void pack_bits(
    const float4* __restrict__ x,   // [T][M4]
    uint4* __restrict__ bm)         // [TW][M4]
{
    const int c4  = blockIdx.x * 256 + threadIdx.x;   // 0..M4-1
    const int twb = blockIdx.y;                       // 0..TW-1

    unsigned w0 = 0, w1 = 0, w2 = 0, w3 = 0;
    const float4* xp = x + (size_t)(twb * 32) * M4 + c4;
    #pragma unroll
    for (int i = 0; i < 32; ++i) {
        float4 v = xp[(size_t)i * M4];
        w0 |= (v.x != 0.0f ? 1u : 0u) << i;
        w1 |= (v.y != 0.0f ? 1u : 0u) << i;
        w2 |= (v.z != 0.0f ? 1u : 0u) << i;
        w3 |= (v.w != 0.0f ? 1u : 0u) << i;
    }
    bm[(size_t)twb * M4 + c4] = make_uint4(w0, w1, w2, w3);
}

// ---- K2: windowed OR -> fp32 ----
// grid (32 colblks, 256 tblks), block 256; each block handles 8
// consecutive t for 1024 cols. Word masks are block-uniform (t is
// uniform); per t: <=5 uint4 L2-hit loads + one contiguous float4 store.
#define TB 8

__global__ __launch_bounds__(256) void window_or(
    const uint4* __restrict__ bm,   // [TW][M4]
    const int*  __restrict__ dur_p,
    float4* __restrict__ out)       // [T][M4]
{
    const int c4 = blockIdx.x * 256 + threadIdx.x;    // 0..M4-1
    const int t0 = blockIdx.y * TB;
    const int duration = dur_p[0];                    // uniform

    #pragma unroll
    for (int k = 0; k < TB; ++k) {
        const int t = t0 + k;
        int L = t - (duration - 1);
        if (L < 0) L = 0;
        const int tw = t >> 5, r  = t & 31;
        const int Lw = L >> 5, Lr = L & 31;

        unsigned ax = 0, ay = 0, az = 0, aw = 0;
        for (int wi = Lw; wi <= tw; ++wi) {
            unsigned m = 0xffffffffu;
            if (wi == tw) m &= (2u << r) - 1u;        // bits [0..r]; r=31 -> all
            if (wi == Lw) m &= ~((1u << Lr) - 1u);    // bits [Lr..31]
            uint4 w = bm[(size_t)wi * M4 + c4];
            ax |= w.x & m; ay |= w.y & m; az |= w.z & m; aw |= w.w & m;
        }
        float4 o;
        o.x = ax ? 1.0f : 0.0f;
        o.y = ay ? 1.0f : 0.0f;
        o.z = az ? 1.0f : 0.0f;
        o.w = aw ? 1.0f : 0.0f;
        out[(size_t)t * M4 + c4] = o;
    }
}

extern "C" void kernel_launch(void* const* d_in, const int* in_sizes, int n_in,
                              void* d_out, int out_size, void* d_ws, size_t ws_size,
                              hipStream_t stream) {
    const float4* x     = (const float4*)d_in[0];
    const int*    dur_p = (const int*)d_in[1];
    float4*       out   = (float4*)d_out;
    uint4*        bm    = (uint4*)d_ws;   // TW*M4*16 = 8.4 MB scratch

    pack_bits<<<dim3(M4 / 256, TW), 256, 0, stream>>>(x, bm);
    window_or<<<dim3(M4 / 256, T_TOTAL / TB), 256, 0, stream>>>(bm, dur_p, out);
}

// Round 5
// 461.030 us; speedup vs baseline: 1.0077x; 1.0077x over previous
//
#include <hip/hip_runtime.h>

// out[t,b,n] = 1 iff any spike in window [t-duration+1, t].
// R5: two-phase via 1-bit intermediate bm[tw][col] (8.4 MB in d_ws).
//   K1 (control, unchanged from R4): fp32 -> bits. Pure 268 MB read,
//       32 independent float4 loads per thread.
//   K2 (rebuilt): LINEAR grid-stride over the flat output. Each 4 KB
//       chunk: 5 clamped, branch-free uint4 window-word loads (L2-hit,
//       MLP 5) + uniform scalar masks + nontemporal float4 store.
//       Write front = contiguous ~4 MB sweeping window (fill-like).

#define T_TOTAL 2048
#define M_COLS  (16 * 2048)        // B*N, fastest axis
#define M4      (M_COLS / 4)       // 8192 float4/uint4 groups per row
#define TW      (T_TOTAL / 32)     // 64 bit-words along t per column

typedef float f32x4 __attribute__((ext_vector_type(4)));

// ---- K1: pack spikes to bits (unchanged control) ----
__global__ __launch_bounds__(256) void pack_bits(
    const float4* __restrict__ x,   // [T][M4]
    uint4* __restrict__ bm)         // [TW][M4]
{
    const int c4  = blockIdx.x * 256 + threadIdx.x;   // 0..M4-1
    const int twb = blockIdx.y;                       // 0..TW-1

    unsigned w0 = 0, w1 = 0, w2 = 0, w3 = 0;
    const float4* xp = x + (size_t)(twb * 32) * M4 + c4;
    #pragma unroll
    for (int i = 0; i < 32; ++i) {
        float4 v = xp[(size_t)i * M4];
        w0 |= (v.x != 0.0f ? 1u : 0u) << i;
        w1 |= (v.y != 0.0f ? 1u : 0u) << i;
        w2 |= (v.z != 0.0f ? 1u : 0u) << i;
        w3 |= (v.w != 0.0f ? 1u : 0u) << i;
    }
    bm[(size_t)twb * M4 + c4] = make_uint4(w0, w1, w2, w3);
}

// ---- K2: linear windowed-OR unpack ----
#define K2_GRID 1024
#define NCHUNK  (T_TOTAL * (M4 / 256))   // 65536 4KB chunks

__global__ __launch_bounds__(256) void window_or_lin(
    const uint4* __restrict__ bm,   // [TW][M4]
    const int*  __restrict__ dur_p,
    float* __restrict__ out)        // flat [T*M_COLS]
{
    const int duration = dur_p[0];  // uniform (100 in practice)
    const int tid = threadIdx.x;

    for (int ci = blockIdx.x; ci < NCHUNK; ci += K2_GRID) {
        const int t  = ci >> 5;                      // row (uniform per chunk)
        const int c4 = ((ci & 31) << 8) + tid;       // 0..M4-1
        int L = t - (duration - 1); if (L < 0) L = 0;
        const int tw = t >> 5, r  = t & 31;
        const int Lw = L >> 5, Lr = L & 31;

        unsigned ax = 0, ay = 0, az = 0, aw = 0;
        if (tw - Lw <= 4) {
            // fixed-depth, branch-free: 5 independent clamped loads
            uint4 w[5];
            #pragma unroll
            for (int j = 0; j < 5; ++j) {
                int wi = Lw + j; if (wi > TW - 1) wi = TW - 1;
                w[j] = bm[(size_t)wi * M4 + c4];
            }
            #pragma unroll
            for (int j = 0; j < 5; ++j) {
                const int wi = Lw + j;
                unsigned m = (wi > tw) ? 0u : 0xffffffffu;
                if (wi == tw) m &= (2u << r) - 1u;        // bits [0..r] (r=31 -> all)
                if (wi == Lw) m &= ~((1u << Lr) - 1u);    // bits [Lr..31]
                ax |= w[j].x & m; ay |= w[j].y & m;
                az |= w[j].z & m; aw |= w[j].w & m;
            }
        } else {
            // generic fallback (never taken for duration<=129)
            for (int wi = Lw; wi <= tw; ++wi) {
                unsigned m = 0xffffffffu;
                if (wi == tw) m &= (2u << r) - 1u;
                if (wi == Lw) m &= ~((1u << Lr) - 1u);
                uint4 w = bm[(size_t)wi * M4 + c4];
                ax |= w.x & m; ay |= w.y & m; az |= w.z & m; aw |= w.w & m;
            }
        }

        f32x4 o;
        o.x = ax ? 1.0f : 0.0f;
        o.y = ay ? 1.0f : 0.0f;
        o.z = az ? 1.0f : 0.0f;
        o.w = aw ? 1.0f : 0.0f;
        __builtin_nontemporal_store(
            o, (f32x4*)(out + ((size_t)ci * 1024 + (size_t)tid * 4)));
    }
}

extern "C" void kernel_launch(void* const* d_in, const int* in_sizes, int n_in,
                              void* d_out, int out_size, void* d_ws, size_t ws_size,
                              hipStream_t stream) {
    const float4* x     = (const float4*)d_in[0];
    const int*    dur_p = (const int*)d_in[1];
    float*        out   = (float*)d_out;
    uint4*        bm    = (uint4*)d_ws;   // TW*M4*16 = 8.4 MB scratch

    pack_bits<<<dim3(M4 / 256, TW), 256, 0, stream>>>(x, bm);
    window_or_lin<<<K2_GRID, 256, 0, stream>>>(bm, dur_p, out);
}